// Round 3
// baseline (283.817 us; speedup 1.0000x reference)
//
#include <hip/hip_runtime.h>

// BiAttention (BiDAF) fused kernels for MI355X / gfx950.
// B=32, C_L=2048, Q_L=256, D=256. Output G = [B][C_L][4*D] fp32.
//
// Round 3: k1 with M=64 tile, 512 thr / 8 waves (wm 0..3 x wn 0..1).
// - A (c*w_cq) staged per K-chunk from ctx as f32 via global_load_lds with a
//   both-sides XOR unit swizzle; split to bf16 hi/lo in registers.
// - B (q hi/lo) staged per chunk, [256][32]-short rows: bank-uniform reads.
// - P stored packed u32 (hi|lo) in LDS halves, word-aligned writes: no
//   bank conflicts. Phase C uses q-hi only (error << threshold).
// - Epilogue: acc2 -> pout LDS halves -> 128B-segment stores of G0/G1/G2.

#define CL 2048
#define QL 256
#define DD 256
#define TM 64
#define NEGV -1.0e7f

typedef short bs8 __attribute__((ext_vector_type(8)));
typedef float fx4 __attribute__((ext_vector_type(4)));
typedef unsigned int ux4 __attribute__((ext_vector_type(4)));

__device__ __forceinline__ short f2bf(float x) {
    unsigned u = __float_as_uint(x);
    unsigned r = (u + 0x7fffu + ((u >> 16) & 1u)) >> 16;   // RNE
    return (short)r;
}
__device__ __forceinline__ float bf2f(short h) {
    return __uint_as_float(((unsigned)(unsigned short)h) << 16);
}
__device__ __forceinline__ void gl16(const short* g, short* l) {
    __builtin_amdgcn_global_load_lds(
        (const __attribute__((address_space(1))) void*)g,
        (__attribute__((address_space(3))) void*)l, 16, 0, 0);
}
__device__ __forceinline__ void gl16f(const float* g, float* l) {
    __builtin_amdgcn_global_load_lds(
        (const __attribute__((address_space(1))) void*)g,
        (__attribute__((address_space(3))) void*)l, 16, 0, 0);
}

// ---------------------------------------------------------------- K0a: split q
// grid (4, 32). 256 threads. Outputs qh/ql ([b][q][d]) and qth ([b][d][q], hi).
__global__ void k0_split(const float* __restrict__ q,
                         short* __restrict__ qh, short* __restrict__ ql,
                         short* __restrict__ qth) {
    __shared__ float lds[64][259];
    int t = threadIdx.x, lane = t & 63, w = t >> 6;
    int b = blockIdx.y, cn = blockIdx.x;
    for (int r = 0; r < 64; ++r)
        lds[r][t] = q[((size_t)b * QL + cn * 64 + r) * DD + t];
    __syncthreads();
    for (int r = 0; r < 64; ++r) {
        float v = lds[r][t];
        short h = f2bf(v);
        short lo = f2bf(v - bf2f(h));
        size_t o = ((size_t)b * QL + cn * 64 + r) * DD + t;
        qh[o] = h; ql[o] = lo;
    }
    for (int dd = 0; dd < 64; ++dd) {
        int d = w * 64 + dd;
        float v = lds[lane][d];
        size_t o = ((size_t)b * DD + d) * QL + cn * 64 + lane;
        qth[o] = f2bf(v);
    }
}

// --------------------------------------------------------------- K0b: s_q dots
__global__ void k0_sq(const float* __restrict__ q, const float* __restrict__ W,
                      float* __restrict__ sq) {
    int t = threadIdx.x, lane = t & 63, w = t >> 6;
    int rowbase = blockIdx.x * 16 + w * 4;
    float4 wq = ((const float4*)(W + DD))[lane];
    for (int rr = 0; rr < 4; ++rr) {
        int row = rowbase + rr;
        float4 v = ((const float4*)q)[(size_t)row * 64 + lane];
        float d = v.x * wq.x + v.y * wq.y + v.z * wq.z + v.w * wq.w;
        for (int s = 32; s >= 1; s >>= 1) d += __shfl_xor(d, s, 64);
        if (lane == 0) sq[row] = d;
    }
}

// ------------------------------------------------------------------- K1: main
// grid (32, 32): blockIdx.x = c-tile (64 rows), blockIdx.y = batch. 512 thr.
__global__ __launch_bounds__(512, 4) void k1(
        const float* __restrict__ ctx, const float* __restrict__ qmask,
        const float* __restrict__ W,
        const short* __restrict__ qh, const short* __restrict__ ql,
        const short* __restrict__ qth,
        const float* __restrict__ sq, float* __restrict__ smax,
        float* __restrict__ G) {
    __shared__ union {
        struct { float Ac[TM][32]; short Bc[2][QL][32]; } pb;   // 8K + 32K
        struct { unsigned Pb[TM][132]; short Qt[QL][32]; } pc;  // 33.8K + 16K
    } U;
    __shared__ float sq_l[QL], qm_l[QL], sc_l[TM];
    __shared__ float wcq_l[DD], wc_l[DD];
    __shared__ float redA[2][2][TM], redB[2][2][TM];

    int t = threadIdx.x, lane = t & 63, wid = t >> 6;
    int wm = wid >> 1, wn = wid & 1;
    int l15 = lane & 15, lk = lane >> 4;
    int b = blockIdx.y, c0 = blockIdx.x * TM;

    if (t < 256) sq_l[t] = sq[b * QL + t];
    else qm_l[t - 256] = qmask[b * QL + (t - 256)];
    if (t < 64) ((float4*)wcq_l)[t] = ((const float4*)W)[128 + t];   // W[512:768]
    else if (t < 128) ((float4*)wc_l)[t - 64] = ((const float4*)W)[t - 64];

    const short* qhb = qh + (size_t)b * QL * DD;
    const short* qlb = ql + (size_t)b * QL * DD;
    const float* ctxb = ctx + ((size_t)b * CL + c0) * DD;

    // ------------------------- Phase B: S-GEMM, 8 chunks of K=32 -------------
    fx4 acc[8];
#pragma unroll
    for (int i = 0; i < 8; ++i) acc[i] = (fx4)0.0f;
    float scp = 0.0f;
    int arow = 16 * wm + l15;

    for (int kk = 0; kk < 8; ++kk) {
        __syncthreads();
        {   // stage A-chunk (f32, unit-swizzled): wave wid -> rows 8wid..+7
            int row = 8 * wid + (lane >> 3);
            int su = (lane & 7) ^ (row & 7);
            gl16f(ctxb + (size_t)row * DD + kk * 32 + su * 4, &U.pb.Ac[8 * wid][0]);
        }
        {   // stage B-chunk: qh/ql rows 32wid..+31
            int r = 32 * wid + (lane >> 2);
            int co = kk * 32 + (lane & 3) * 8;
            gl16(qhb + (size_t)r * DD + co,        &U.pb.Bc[0][32 * wid][0]);
            gl16(qhb + (size_t)(r + 16) * DD + co, &U.pb.Bc[0][32 * wid + 16][0]);
            gl16(qlb + (size_t)r * DD + co,        &U.pb.Bc[1][32 * wid][0]);
            gl16(qlb + (size_t)(r + 16) * DD + co, &U.pb.Bc[1][32 * wid + 16][0]);
        }
        asm volatile("s_waitcnt vmcnt(0)" ::: "memory");
        __syncthreads();

        // A-frag: f32 units (swizzle-aware), split to bf16 hi/lo in regs.
        fx4 a0 = *(const fx4*)&U.pb.Ac[arow][((2 * lk)     ^ (arow & 7)) * 4];
        fx4 a1 = *(const fx4*)&U.pb.Ac[arow][((2 * lk + 1) ^ (arow & 7)) * 4];
        fx4 w0 = *(const fx4*)&wcq_l[kk * 32 + lk * 8];
        fx4 w1 = *(const fx4*)&wcq_l[kk * 32 + lk * 8 + 4];
        fx4 v0 = *(const fx4*)&wc_l[kk * 32 + lk * 8];
        fx4 v1 = *(const fx4*)&wc_l[kk * 32 + lk * 8 + 4];
        scp += a0[0] * v0[0] + a0[1] * v0[1] + a0[2] * v0[2] + a0[3] * v0[3]
             + a1[0] * v1[0] + a1[1] * v1[1] + a1[2] * v1[2] + a1[3] * v1[3];
        bs8 Ah, Al;
#pragma unroll
        for (int i = 0; i < 4; ++i) {
            float a = a0[i] * w0[i];
            short h = f2bf(a); Ah[i] = h; Al[i] = f2bf(a - bf2f(h));
            float c = a1[i] * w1[i];
            short h2 = f2bf(c); Ah[4 + i] = h2; Al[4 + i] = f2bf(c - bf2f(h2));
        }
#pragma unroll
        for (int nt = 0; nt < 8; ++nt) {
            int col = 128 * wn + 16 * nt + l15;
            bs8 Bh = *(const bs8*)&U.pb.Bc[0][col][lk * 8];
            bs8 Bl = *(const bs8*)&U.pb.Bc[1][col][lk * 8];
            acc[nt] = __builtin_amdgcn_mfma_f32_16x16x32_bf16(Ah, Bh, acc[nt], 0, 0, 0);
            acc[nt] = __builtin_amdgcn_mfma_f32_16x16x32_bf16(Ah, Bl, acc[nt], 0, 0, 0);
            acc[nt] = __builtin_amdgcn_mfma_f32_16x16x32_bf16(Al, Bh, acc[nt], 0, 0, 0);
        }
    }
    // s_c: reduce over lk (lanes sharing l15), write once.
    scp += __shfl_xor(scp, 16, 64);
    scp += __shfl_xor(scp, 32, 64);
    if (lk == 0 && wn == 0) sc_l[arow] = scp;
    __syncthreads();

    // ------------------------- Softmax over q --------------------------------
    float mall[4], mu[4], scv[4];
#pragma unroll
    for (int j = 0; j < 4; ++j) {
        mall[j] = -3.0e38f; mu[j] = -3.0e38f;
        scv[j] = sc_l[16 * wm + 4 * lk + j];
    }
#pragma unroll
    for (int nt = 0; nt < 8; ++nt) {
        int col = 128 * wn + 16 * nt + l15;
        float sqv = sq_l[col], qmv = qm_l[col];
#pragma unroll
        for (int j = 0; j < 4; ++j) {
            float S = acc[nt][j] + scv[j] + sqv;
            float xm = S * qmv;
            float ms = (qmv != 0.0f) ? S : NEGV;
            acc[nt][j] = xm;
            mall[j] = fmaxf(mall[j], xm);
            mu[j]   = fmaxf(mu[j], ms);
        }
    }
#pragma unroll
    for (int s = 1; s <= 8; s <<= 1)
#pragma unroll
        for (int j = 0; j < 4; ++j) {
            mall[j] = fmaxf(mall[j], __shfl_xor(mall[j], s, 64));
            mu[j]   = fmaxf(mu[j],   __shfl_xor(mu[j], s, 64));
        }
    if (l15 == 0)
#pragma unroll
        for (int j = 0; j < 4; ++j) {
            redA[wn][0][16 * wm + 4 * lk + j] = mall[j];
            redA[wn][1][16 * wm + 4 * lk + j] = mu[j];
        }
    __syncthreads();
#pragma unroll
    for (int j = 0; j < 4; ++j) {
        int row = 16 * wm + 4 * lk + j;
        mall[j] = fmaxf(redA[0][0][row], redA[1][0][row]);
        mu[j]   = fmaxf(redA[0][1][row], redA[1][1][row]);
    }
    if (wn == 0 && l15 == 0)
#pragma unroll
        for (int j = 0; j < 4; ++j)
            smax[(size_t)b * CL + c0 + 16 * wm + 4 * lk + j] = mu[j];

    float zal[4] = {0, 0, 0, 0}, zum[4] = {0, 0, 0, 0};
#pragma unroll
    for (int nt = 0; nt < 8; ++nt) {
        int col = 128 * wn + 16 * nt + l15;
        float qmv = qm_l[col];
#pragma unroll
        for (int j = 0; j < 4; ++j) {
            float e = __expf(acc[nt][j] - mall[j]);
            acc[nt][j] = e;
            zal[j] += e;
            zum[j] += e * qmv;
        }
    }
#pragma unroll
    for (int s = 1; s <= 8; s <<= 1)
#pragma unroll
        for (int j = 0; j < 4; ++j) {
            zal[j] += __shfl_xor(zal[j], s, 64);
            zum[j] += __shfl_xor(zum[j], s, 64);
        }
    if (l15 == 0)
#pragma unroll
        for (int j = 0; j < 4; ++j) {
            redB[wn][0][16 * wm + 4 * lk + j] = zal[j];
            redB[wn][1][16 * wm + 4 * lk + j] = zum[j];
        }
    __syncthreads();
    float inv[4];
#pragma unroll
    for (int j = 0; j < 4; ++j) {
        int row = 16 * wm + 4 * lk + j;
        float Za = redB[0][0][row] + redB[1][0][row];
        float Zu = redB[0][1][row] + redB[1][1][row];
        inv[j] = 1.0f / (Zu + 1e-13f * Za);
    }

    // ------------------------- Phase C: c2q, in q-halves ---------------------
    fx4 acc2[8];
#pragma unroll
    for (int i = 0; i < 8; ++i) acc2[i] = (fx4)0.0f;
    const short* qtb = qth + (size_t)b * DD * QL;
    int prow = 16 * wm + l15;

    for (int h = 0; h < 2; ++h) {
        __syncthreads();                       // prior Pb/Qt readers done
        if (wn == h) {
#pragma unroll
            for (int nt = 0; nt < 8; ++nt) {
                int colL = 16 * nt + l15;
                float qmv = qm_l[128 * h + colL];
#pragma unroll
                for (int j = 0; j < 4; ++j) {
                    int row = 16 * wm + 4 * lk + j;
                    float p = acc[nt][j] * qmv * inv[j];
                    short hi = f2bf(p);
                    short lo = f2bf(p - bf2f(hi));
                    U.pc.Pb[row][colL] =
                        ((unsigned)(unsigned short)hi << 16) | (unsigned short)lo;
                }
            }
        }
        for (int k2 = 0; k2 < 4; ++k2) {
            __syncthreads();                   // P visible / prev Qt consumed
            int gk = h * 128 + k2 * 32;
            int r = 32 * wid + (lane >> 2);
            int co = gk + (lane & 3) * 8;
            gl16(qtb + (size_t)r * QL + co,        &U.pc.Qt[32 * wid][0]);
            gl16(qtb + (size_t)(r + 16) * QL + co, &U.pc.Qt[32 * wid + 16][0]);
            asm volatile("s_waitcnt vmcnt(0)" ::: "memory");
            __syncthreads();

            ux4 pw0 = *(const ux4*)&U.pc.Pb[prow][k2 * 32 + lk * 8];
            ux4 pw1 = *(const ux4*)&U.pc.Pb[prow][k2 * 32 + lk * 8 + 4];
            bs8 Ph, Pl;
#pragma unroll
            for (int i = 0; i < 4; ++i) {
                Ph[i]     = (short)(pw0[i] >> 16);
                Pl[i]     = (short)(pw0[i] & 0xffffu);
                Ph[4 + i] = (short)(pw1[i] >> 16);
                Pl[4 + i] = (short)(pw1[i] & 0xffffu);
            }
#pragma unroll
            for (int nt = 0; nt < 8; ++nt) {
                int d = 128 * wn + 16 * nt + l15;
                bs8 Bh = *(const bs8*)&U.pc.Qt[d][lk * 8];
                acc2[nt] = __builtin_amdgcn_mfma_f32_16x16x32_bf16(Ph, Bh, acc2[nt], 0, 0, 0);
                acc2[nt] = __builtin_amdgcn_mfma_f32_16x16x32_bf16(Pl, Bh, acc2[nt], 0, 0, 0);
            }
        }
    }

    // ------------------------- Epilogue: G0/G1/G2, in d-halves ---------------
    float* pout = (float*)&U.pc.Pb[0][0];      // [64][132]
    int erow = t >> 3, eu = t & 7;
    for (int h = 0; h < 2; ++h) {
        __syncthreads();                       // phase C / prev half reads done
        if (wn == h) {
#pragma unroll
            for (int nt = 0; nt < 8; ++nt)
#pragma unroll
                for (int j = 0; j < 4; ++j)
                    pout[(16 * wm + 4 * lk + j) * 132 + 16 * nt + l15] = acc2[nt][j];
        }
        __syncthreads();
        size_t grow = (size_t)b * CL + c0 + erow;
#pragma unroll
        for (int kkl = 0; kkl < 4; ++kkl) {
            int colL = kkl * 32 + eu * 4;
            fx4 cv = *(const fx4*)&ctxb[(size_t)erow * DD + 128 * h + colL];
            fx4 pv = *(const fx4*)&pout[erow * 132 + colL];
            float* gb = G + grow * 1024;
            *(fx4*)&gb[      128 * h + colL] = cv;
            *(fx4*)&gb[256 + 128 * h + colL] = pv;
            fx4 p2; p2[0] = cv[0] * pv[0]; p2[1] = cv[1] * pv[1];
            p2[2] = cv[2] * pv[2]; p2[3] = cv[3] * pv[3];
            *(fx4*)&gb[512 + 128 * h + colL] = p2;
        }
    }
}

// ------------------------------------------------- K2a: e_c + partial Z sums
__global__ void k2a(const float* __restrict__ smax, const float* __restrict__ cmask,
                    float* __restrict__ ec, float* __restrict__ zup,
                    float* __restrict__ zap) {
    __shared__ float r1[4], r2[4];
    int t = threadIdx.x, lane = t & 63, w = t >> 6;
    int b = blockIdx.y;
    size_t c = (size_t)b * CL + blockIdx.x * 256 + t;
    float sm = smax[c], cm = cmask[c];
    float e  = (cm != 0.0f) ? __expf(sm - 32.0f) : 0.0f;
    float za = (cm != 0.0f) ? e : 1.2664166e-14f;              // exp(-32)
    ec[c] = e;
    float s1 = e, s2 = za;
    for (int s = 32; s >= 1; s >>= 1) {
        s1 += __shfl_xor(s1, s, 64);
        s2 += __shfl_xor(s2, s, 64);
    }
    if (lane == 0) { r1[w] = s1; r2[w] = s2; }
    __syncthreads();
    if (t == 0) {
        zup[b * 8 + blockIdx.x] = r1[0] + r1[1] + r1[2] + r1[3];
        zap[b * 8 + blockIdx.x] = r2[0] + r2[1] + r2[2] + r2[3];
    }
}

// ------------------------------------------------- K2b: q2c partial reductions
__global__ void k2b(const float* __restrict__ ctx, const float* __restrict__ ec,
                    float* __restrict__ q2cp) {
    __shared__ float ew[128];
    int t = threadIdx.x;
    int b = blockIdx.y, ch = blockIdx.x;
    if (t < 128) ew[t] = ec[(size_t)b * CL + ch * 128 + t];
    __syncthreads();
    float acc = 0.0f;
    for (int r = 0; r < 128; ++r)
        acc = fmaf(ew[r], ctx[((size_t)b * CL + ch * 128 + r) * DD + t], acc);
    q2cp[((size_t)b * 16 + ch) * DD + t] = acc;
}

// ------------------------------------------------- K2c: finalize q2c (determ.)
__global__ void k2c(const float* __restrict__ q2cp, const float* __restrict__ zup,
                    const float* __restrict__ zap, float* __restrict__ q2c) {
    int t = threadIdx.x, b = blockIdx.x;
    float zu = 0.0f, za = 0.0f;
    for (int i = 0; i < 8; ++i) { zu += zup[b * 8 + i]; za += zap[b * 8 + i]; }
    float inv = 1.0f / (zu + 1e-13f * za);
    float s = 0.0f;
    for (int ch = 0; ch < 16; ++ch) s += q2cp[((size_t)b * 16 + ch) * DD + t];
    q2c[b * DD + t] = s * inv;
}

// ------------------------------------------------- K3: G part 3 = c * q2c
__global__ void k3(const float* __restrict__ ctx, const float* __restrict__ q2c,
                   float* __restrict__ G) {
    __shared__ float4 qv[64];
    int t = threadIdx.x, lane = t & 63, w = t >> 6;
    int b = blockIdx.y;
    if (t < 64) qv[t] = ((const float4*)q2c)[b * 64 + t];
    __syncthreads();
    int c0 = blockIdx.x * 16;
    float4 q4 = qv[lane];
    for (int r = w; r < 16; r += 4) {
        size_t grow = (size_t)b * CL + c0 + r;
        float4 cv = ((const float4*)ctx)[grow * 64 + lane];
        float4 o;
        o.x = cv.x * q4.x; o.y = cv.y * q4.y;
        o.z = cv.z * q4.z; o.w = cv.w * q4.w;
        ((float4*)G)[grow * 256 + 192 + lane] = o;
    }
}

extern "C" void kernel_launch(void* const* d_in, const int* in_sizes, int n_in,
                              void* d_out, int out_size, void* d_ws, size_t ws_size,
                              hipStream_t stream) {
    const float* ctx   = (const float*)d_in[0];
    const float* cmask = (const float*)d_in[1];
    const float* q     = (const float*)d_in[2];
    const float* qmask = (const float*)d_in[3];
    const float* W     = (const float*)d_in[4];
    float* G = (float*)d_out;

    char* ws = (char*)d_ws;
    if (ws_size < (size_t)14680064) return;   // ~14 MiB
    short* qh  = (short*)(ws);                        // 4 MiB
    short* ql  = (short*)(ws + 4194304);              // 4 MiB
    short* qth = (short*)(ws + 8388608);              // 4 MiB
    float* sq   = (float*)(ws + 12582912);            // 32 KiB
    float* smax = (float*)(ws + 12615680);            // 256 KiB
    float* ec   = (float*)(ws + 12877824);            // 256 KiB
    float* zup  = (float*)(ws + 13139968);            // 1 KiB
    float* zap  = (float*)(ws + 13141020);            // 1 KiB (pad-safe)
    float* q2cp = (float*)(ws + 13144064);            // 512 KiB
    float* q2cv = (float*)(ws + 13668352);            // 32 KiB

    k0_split<<<dim3(4, 32), dim3(256), 0, stream>>>(q, qh, ql, qth);
    k0_sq<<<dim3(512), dim3(256), 0, stream>>>(q, W, sq);
    k1<<<dim3(32, 32), dim3(512), 0, stream>>>(ctx, qmask, W, qh, ql, qth,
                                               sq, smax, G);
    k2a<<<dim3(8, 32), dim3(256), 0, stream>>>(smax, cmask, ec, zup, zap);
    k2b<<<dim3(16, 32), dim3(256), 0, stream>>>(ctx, ec, q2cp);
    k2c<<<dim3(32), dim3(256), 0, stream>>>(q2cp, zup, zap, q2cv);
    k3<<<dim3(128, 32), dim3(256), 0, stream>>>(ctx, q2cv, G);
}

// Round 4
// 208.908 us; speedup vs baseline: 1.3586x; 1.3586x over previous
//
#include <hip/hip_runtime.h>

// BiAttention (BiDAF) fused kernels for MI355X / gfx950.
// B=32, C_L=2048, Q_L=256, D=256. Output G = [B][C_L][4*D] fp32.
//
// Round 4:
// - Both-sides XOR swizzle restored on Bc/Qt staging+reads (round-2-verified
//   bank-uniform: phys_sub = log_sub ^ ((row>>1)&3)).
// - T3 2-phase pipeline: Bc/Qt double-buffered, next chunk staged before
//   current compute, one __syncthreads drain per chunk.
// - A-operand fragments gathered straight to registers (prefetched), no A LDS.
// - q2c path fused into k1 via fixed-offset exp (no global max needed):
//   per-block partial Sum(e_c * c), partial Zu/Za; k2a/k2b eliminated.
// - s_q dots fused into k0_split.

#define CL 2048
#define QL 256
#define DD 256
#define TM 64
#define NEGV -1.0e7f

typedef short bs8 __attribute__((ext_vector_type(8)));
typedef float fx4 __attribute__((ext_vector_type(4)));
typedef unsigned int ux4 __attribute__((ext_vector_type(4)));

__device__ __forceinline__ short f2bf(float x) {
    unsigned u = __float_as_uint(x);
    unsigned r = (u + 0x7fffu + ((u >> 16) & 1u)) >> 16;   // RNE
    return (short)r;
}
__device__ __forceinline__ float bf2f(short h) {
    return __uint_as_float(((unsigned)(unsigned short)h) << 16);
}
__device__ __forceinline__ void gl16(const short* g, short* l) {
    __builtin_amdgcn_global_load_lds(
        (const __attribute__((address_space(1))) void*)g,
        (__attribute__((address_space(3))) void*)l, 16, 0, 0);
}

// ------------------------------------------- K0: split q (+ transposed) + s_q
// grid (4, 32). 256 threads.
__global__ void k0_split(const float* __restrict__ q, const float* __restrict__ W,
                         short* __restrict__ qh, short* __restrict__ ql,
                         short* __restrict__ qth, float* __restrict__ sq) {
    __shared__ float lds[64][259];
    __shared__ float wq_l[256];
    int t = threadIdx.x, lane = t & 63, w = t >> 6;
    int b = blockIdx.y, cn = blockIdx.x;
    if (t < 64) *(fx4*)&wq_l[t * 4] = *(const fx4*)(W + 256 + t * 4);
    for (int r = 0; r < 64; ++r)
        lds[r][t] = q[((size_t)b * QL + cn * 64 + r) * DD + t];
    __syncthreads();
    // natural split [b][q][d]
    for (int r = 0; r < 64; ++r) {
        float v = lds[r][t];
        short h = f2bf(v);
        short lo = f2bf(v - bf2f(h));
        size_t o = ((size_t)b * QL + cn * 64 + r) * DD + t;
        qh[o] = h; ql[o] = lo;
    }
    // transposed hi [b][d][q]
    for (int dd = 0; dd < 64; ++dd) {
        int d = w * 64 + dd;
        float v = lds[lane][d];
        size_t o = ((size_t)b * DD + d) * QL + cn * 64 + lane;
        qth[o] = f2bf(v);
    }
    // s_q: row r = t>>2, quarter qt = t&3, rotated start to spread banks.
    int r = t >> 2, qt = t & 3;
    float s = 0.0f;
    for (int i = 0; i < 64; ++i) {
        int colr = qt * 64 + ((i + r) & 63);
        s = fmaf(lds[r][colr], wq_l[colr], s);
    }
    s += __shfl_xor(s, 1, 64);
    s += __shfl_xor(s, 2, 64);
    if (qt == 0) sq[b * QL + cn * 64 + r] = s;
}

// ------------------------------------------------------------------- K1: main
// grid (32, 32): blockIdx.x = c-tile (64 rows), blockIdx.y = batch. 512 thr.
__global__ __launch_bounds__(512, 4) void k1(
        const float* __restrict__ ctx, const float* __restrict__ qmask,
        const float* __restrict__ cmask,
        const short* __restrict__ qh, const short* __restrict__ ql,
        const short* __restrict__ qth,
        const float* __restrict__ sq, const float* __restrict__ W,
        float* __restrict__ G, float* __restrict__ q2cp,
        float* __restrict__ zup, float* __restrict__ zap) {
    __shared__ union {
        short Bc[2][2][QL][32];                                  // 64 KB
        struct { unsigned Pb[TM][132]; short Qt[2][QL][32]; } pc; // 33.8+32 KB
    } U;
    __shared__ float sq_l[QL], qm_l[QL], sc_l[TM];
    __shared__ float wcq_l[DD], wc_l[DD];
    __shared__ float redA[2][2][TM], redB[2][2][TM];
    __shared__ float er_l[TM], zar_l[TM];

    int t = threadIdx.x, lane = t & 63, wid = t >> 6;
    int wm = wid >> 1, wn = wid & 1;
    int l15 = lane & 15, lk = lane >> 4;
    int b = blockIdx.y, bx = blockIdx.x, c0 = bx * TM;

    if (t < 256) sq_l[t] = sq[b * QL + t];
    else qm_l[t - 256] = qmask[b * QL + (t - 256)];
    if (t < 64) *(fx4*)&wcq_l[t * 4] = *(const fx4*)(W + 512 + t * 4);
    else if (t < 128) *(fx4*)&wc_l[(t - 64) * 4] = *(const fx4*)(W + (t - 64) * 4);

    const short* qhb = qh + (size_t)b * QL * DD;
    const short* qlb = ql + (size_t)b * QL * DD;
    const short* qtb = qth + (size_t)b * DD * QL;
    const float* ctxb = ctx + ((size_t)b * CL + c0) * DD;

    int srow = 32 * wid + (lane >> 2);
    int ssub = ((lane & 3) ^ ((srow >> 1) & 3)) << 3;   // source pre-swizzle

    auto stageB = [&](int p, int kk) {
        int co = kk * 32 + ssub;
        gl16(qhb + (size_t)srow * DD + co,        &U.Bc[p][0][32 * wid][0]);
        gl16(qhb + (size_t)(srow + 16) * DD + co, &U.Bc[p][0][32 * wid + 16][0]);
        gl16(qlb + (size_t)srow * DD + co,        &U.Bc[p][1][32 * wid][0]);
        gl16(qlb + (size_t)(srow + 16) * DD + co, &U.Bc[p][1][32 * wid + 16][0]);
    };
    auto stageQt = [&](int p, int s) {
        int co = (s >> 2) * 128 + (s & 3) * 32 + ssub;
        gl16(qtb + (size_t)srow * QL + co,        &U.pc.Qt[p][32 * wid][0]);
        gl16(qtb + (size_t)(srow + 16) * QL + co, &U.pc.Qt[p][32 * wid + 16][0]);
    };

    // ---------------- Phase B: S-GEMM, 8 chunks of K=32, pipelined ----------
    fx4 acc[8];
#pragma unroll
    for (int i = 0; i < 8; ++i) acc[i] = (fx4)0.0f;
    float scp = 0.0f;
    int arow = 16 * wm + l15;
    const float* aptr = ctxb + (size_t)arow * DD + lk * 8;

    stageB(0, 0);
    fx4 a0 = *(const fx4*)(aptr);
    fx4 a1 = *(const fx4*)(aptr + 4);
    __syncthreads();

#pragma unroll
    for (int kk = 0; kk < 8; ++kk) {
        int cur = kk & 1;
        fx4 n0, n1;
        if (kk < 7) {
            stageB(cur ^ 1, kk + 1);
            n0 = *(const fx4*)(aptr + (kk + 1) * 32);
            n1 = *(const fx4*)(aptr + (kk + 1) * 32 + 4);
        }
        fx4 w0 = *(const fx4*)&wcq_l[kk * 32 + lk * 8];
        fx4 w1 = *(const fx4*)&wcq_l[kk * 32 + lk * 8 + 4];
        fx4 v0 = *(const fx4*)&wc_l[kk * 32 + lk * 8];
        fx4 v1 = *(const fx4*)&wc_l[kk * 32 + lk * 8 + 4];
        scp += a0[0] * v0[0] + a0[1] * v0[1] + a0[2] * v0[2] + a0[3] * v0[3]
             + a1[0] * v1[0] + a1[1] * v1[1] + a1[2] * v1[2] + a1[3] * v1[3];
        bs8 Ah, Al;
#pragma unroll
        for (int i = 0; i < 4; ++i) {
            float a = a0[i] * w0[i];
            short h = f2bf(a); Ah[i] = h; Al[i] = f2bf(a - bf2f(h));
            float c = a1[i] * w1[i];
            short h2 = f2bf(c); Ah[4 + i] = h2; Al[4 + i] = f2bf(c - bf2f(h2));
        }
#pragma unroll
        for (int nt = 0; nt < 8; ++nt) {
            int col = 128 * wn + 16 * nt + l15;
            int ko = ((lk ^ ((col >> 1) & 3)) << 3);        // swizzled read
            bs8 Bh = *(const bs8*)&U.Bc[cur][0][col][ko];
            bs8 Bl = *(const bs8*)&U.Bc[cur][1][col][ko];
            acc[nt] = __builtin_amdgcn_mfma_f32_16x16x32_bf16(Ah, Bh, acc[nt], 0, 0, 0);
            acc[nt] = __builtin_amdgcn_mfma_f32_16x16x32_bf16(Ah, Bl, acc[nt], 0, 0, 0);
            acc[nt] = __builtin_amdgcn_mfma_f32_16x16x32_bf16(Al, Bh, acc[nt], 0, 0, 0);
        }
        __syncthreads();   // drains vmcnt: next Bc + A-prefetch complete
        a0 = n0; a1 = n1;
    }
    // s_c: reduce over lk, write once per row.
    scp += __shfl_xor(scp, 16, 64);
    scp += __shfl_xor(scp, 32, 64);
    if (lk == 0 && wn == 0) sc_l[arow] = scp;
    __syncthreads();

    // ---------------- Softmax over q ----------------------------------------
    float mall[4], mu[4], scv[4];
#pragma unroll
    for (int j = 0; j < 4; ++j) {
        mall[j] = -3.0e38f; mu[j] = -3.0e38f;
        scv[j] = sc_l[16 * wm + 4 * lk + j];
    }
#pragma unroll
    for (int nt = 0; nt < 8; ++nt) {
        int col = 128 * wn + 16 * nt + l15;
        float sqv = sq_l[col], qmv = qm_l[col];
#pragma unroll
        for (int j = 0; j < 4; ++j) {
            float S = acc[nt][j] + scv[j] + sqv;
            float xm = S * qmv;
            float ms = (qmv != 0.0f) ? S : NEGV;
            acc[nt][j] = xm;
            mall[j] = fmaxf(mall[j], xm);
            mu[j]   = fmaxf(mu[j], ms);
        }
    }
#pragma unroll
    for (int s = 1; s <= 8; s <<= 1)
#pragma unroll
        for (int j = 0; j < 4; ++j) {
            mall[j] = fmaxf(mall[j], __shfl_xor(mall[j], s, 64));
            mu[j]   = fmaxf(mu[j],   __shfl_xor(mu[j], s, 64));
        }
    if (l15 == 0)
#pragma unroll
        for (int j = 0; j < 4; ++j) {
            redA[wn][0][16 * wm + 4 * lk + j] = mall[j];
            redA[wn][1][16 * wm + 4 * lk + j] = mu[j];
        }
    __syncthreads();
#pragma unroll
    for (int j = 0; j < 4; ++j) {
        int row = 16 * wm + 4 * lk + j;
        mall[j] = fmaxf(redA[0][0][row], redA[1][0][row]);
        mu[j]   = fmaxf(redA[0][1][row], redA[1][1][row]);
    }
    // e_c / Za contributions for the q2c path (fixed offset -32, no max).
    if (wn == 0 && l15 == 0)
#pragma unroll
        for (int j = 0; j < 4; ++j) {
            int row = 16 * wm + 4 * lk + j;
            float cm = cmask[(size_t)b * CL + c0 + row];
            float e  = (cm != 0.0f) ? __expf(mu[j] - 32.0f) : 0.0f;
            er_l[row]  = e;
            zar_l[row] = (cm != 0.0f) ? e : 1.2664166e-14f;   // exp(-32)
        }

    float zal[4] = {0, 0, 0, 0}, zum[4] = {0, 0, 0, 0};
#pragma unroll
    for (int nt = 0; nt < 8; ++nt) {
        int col = 128 * wn + 16 * nt + l15;
        float qmv = qm_l[col];
#pragma unroll
        for (int j = 0; j < 4; ++j) {
            float e = __expf(acc[nt][j] - mall[j]);
            acc[nt][j] = e;
            zal[j] += e;
            zum[j] += e * qmv;
        }
    }
#pragma unroll
    for (int s = 1; s <= 8; s <<= 1)
#pragma unroll
        for (int j = 0; j < 4; ++j) {
            zal[j] += __shfl_xor(zal[j], s, 64);
            zum[j] += __shfl_xor(zum[j], s, 64);
        }
    if (l15 == 0)
#pragma unroll
        for (int j = 0; j < 4; ++j) {
            redB[wn][0][16 * wm + 4 * lk + j] = zal[j];
            redB[wn][1][16 * wm + 4 * lk + j] = zum[j];
        }
    __syncthreads();
    float inv[4];
#pragma unroll
    for (int j = 0; j < 4; ++j) {
        int row = 16 * wm + 4 * lk + j;
        float Za = redB[0][0][row] + redB[1][0][row];
        float Zu = redB[0][1][row] + redB[1][1][row];
        inv[j] = 1.0f / (Zu + 1e-13f * Za);
    }

    // ---------------- Phase C: c2q = P @ q, pipelined, P in half-buffers -----
    int prow = 16 * wm + l15;
    if (wn == 0) {                                   // write P half 0
#pragma unroll
        for (int nt = 0; nt < 8; ++nt) {
            int colL = 16 * nt + l15;
            float qmv = qm_l[colL];
#pragma unroll
            for (int j = 0; j < 4; ++j) {
                int row = 16 * wm + 4 * lk + j;
                float p = acc[nt][j] * qmv * inv[j];
                short hi = f2bf(p);
                short lo = f2bf(p - bf2f(hi));
                U.pc.Pb[row][colL] =
                    ((unsigned)(unsigned short)hi << 16) | (unsigned short)lo;
            }
        }
    }
    stageQt(0, 0);
    __syncthreads();

    fx4 acc2[8];
#pragma unroll
    for (int i = 0; i < 8; ++i) acc2[i] = (fx4)0.0f;
#pragma unroll
    for (int s = 0; s < 8; ++s) {
        int cur = s & 1;
        if (s < 7) stageQt(cur ^ 1, s + 1);
        int k2 = s & 3;
        ux4 pw0 = *(const ux4*)&U.pc.Pb[prow][k2 * 32 + lk * 8];
        ux4 pw1 = *(const ux4*)&U.pc.Pb[prow][k2 * 32 + lk * 8 + 4];
        bs8 Ph, Pl;
#pragma unroll
        for (int i = 0; i < 4; ++i) {
            Ph[i]     = (short)(pw0[i] >> 16);
            Pl[i]     = (short)(pw0[i] & 0xffffu);
            Ph[4 + i] = (short)(pw1[i] >> 16);
            Pl[4 + i] = (short)(pw1[i] & 0xffffu);
        }
#pragma unroll
        for (int nt = 0; nt < 8; ++nt) {
            int d = 128 * wn + 16 * nt + l15;
            int ko = ((lk ^ ((d >> 1) & 3)) << 3);
            bs8 Bh = *(const bs8*)&U.pc.Qt[cur][d][ko];
            acc2[nt] = __builtin_amdgcn_mfma_f32_16x16x32_bf16(Ph, Bh, acc2[nt], 0, 0, 0);
            acc2[nt] = __builtin_amdgcn_mfma_f32_16x16x32_bf16(Pl, Bh, acc2[nt], 0, 0, 0);
        }
        if (s == 3) {
            __syncthreads();                          // all half-0 P reads done
            if (wn == 1) {                            // write P half 1
#pragma unroll
                for (int nt = 0; nt < 8; ++nt) {
                    int colL = 16 * nt + l15;
                    float qmv = qm_l[128 + colL];
#pragma unroll
                    for (int j = 0; j < 4; ++j) {
                        int row = 16 * wm + 4 * lk + j;
                        float p = acc[nt][j] * qmv * inv[j];
                        short hi = f2bf(p);
                        short lo = f2bf(p - bf2f(hi));
                        U.pc.Pb[row][colL] =
                            ((unsigned)(unsigned short)hi << 16) | (unsigned short)lo;
                    }
                }
            }
        }
        __syncthreads();
    }

    // ---------------- Epilogue: G0/G1/G2 in d-halves -------------------------
    float* pout = (float*)&U.pc.Pb[0][0];            // [64][132] f32
    int erow = t >> 3, eu = t & 7;
    for (int h = 0; h < 2; ++h) {
        if (h) __syncthreads();
        if (wn == h) {
#pragma unroll
            for (int nt = 0; nt < 8; ++nt)
#pragma unroll
                for (int j = 0; j < 4; ++j)
                    pout[(16 * wm + 4 * lk + j) * 132 + 16 * nt + l15] = acc2[nt][j];
        }
        __syncthreads();
        size_t grow = (size_t)b * CL + c0 + erow;
#pragma unroll
        for (int kkl = 0; kkl < 4; ++kkl) {
            int colL = kkl * 32 + eu * 4;
            fx4 cv = *(const fx4*)&ctxb[(size_t)erow * DD + 128 * h + colL];
            fx4 pv = *(const fx4*)&pout[erow * 132 + colL];
            float* gb = G + grow * 1024;
            *(fx4*)&gb[      128 * h + colL] = cv;
            *(fx4*)&gb[256 + 128 * h + colL] = pv;
            fx4 p2; p2[0] = cv[0] * pv[0]; p2[1] = cv[1] * pv[1];
            p2[2] = cv[2] * pv[2]; p2[3] = cv[3] * pv[3];
            *(fx4*)&gb[512 + 128 * h + colL] = p2;
        }
    }

    // ---------------- q2c partials: Sum_r e_r * c[r][col], Zu/Za -------------
    int colq = t & 255, rh = t >> 8;
    float accq = 0.0f;
#pragma unroll 8
    for (int r = rh * 32; r < rh * 32 + 32; ++r)
        accq = fmaf(er_l[r], ctxb[(size_t)r * DD + colq], accq);
    q2cp[(((size_t)b * 32 + bx) * 2 + rh) * 256 + colq] = accq;
    if (t < 64) {
        float e = er_l[t], za = zar_l[t];
#pragma unroll
        for (int sft = 32; sft >= 1; sft >>= 1) {
            e  += __shfl_xor(e, sft, 64);
            za += __shfl_xor(za, sft, 64);
        }
        if (t == 0) { zup[b * 32 + bx] = e; zap[b * 32 + bx] = za; }
    }
}

// ------------------------------------------------- K2c: finalize q2c (determ.)
__global__ void k2c(const float* __restrict__ q2cp, const float* __restrict__ zup,
                    const float* __restrict__ zap, float* __restrict__ q2c) {
    int t = threadIdx.x, b = blockIdx.x;
    float zu = 0.0f, za = 0.0f;
    for (int i = 0; i < 32; ++i) { zu += zup[b * 32 + i]; za += zap[b * 32 + i]; }
    float inv = 1.0f / (zu + 1e-13f * za);
    float s = 0.0f;
    for (int p = 0; p < 64; ++p) s += q2cp[((size_t)b * 64 + p) * 256 + t];
    q2c[b * DD + t] = s * inv;
}

// ------------------------------------------------- K3: G part 3 = c * q2c
__global__ void k3(const float* __restrict__ ctx, const float* __restrict__ q2c,
                   float* __restrict__ G) {
    __shared__ float4 qv[64];
    int t = threadIdx.x, lane = t & 63, w = t >> 6;
    int b = blockIdx.y;
    if (t < 64) qv[t] = ((const float4*)q2c)[b * 64 + t];
    __syncthreads();
    int c0 = blockIdx.x * 16;
    float4 q4 = qv[lane];
    for (int r = w; r < 16; r += 4) {
        size_t grow = (size_t)b * CL + c0 + r;
        float4 cv = ((const float4*)ctx)[grow * 64 + lane];
        float4 o;
        o.x = cv.x * q4.x; o.y = cv.y * q4.y;
        o.z = cv.z * q4.z; o.w = cv.w * q4.w;
        ((float4*)G)[grow * 256 + 192 + lane] = o;
    }
}

extern "C" void kernel_launch(void* const* d_in, const int* in_sizes, int n_in,
                              void* d_out, int out_size, void* d_ws, size_t ws_size,
                              hipStream_t stream) {
    const float* ctx   = (const float*)d_in[0];
    const float* cmask = (const float*)d_in[1];
    const float* q     = (const float*)d_in[2];
    const float* qmask = (const float*)d_in[3];
    const float* W     = (const float*)d_in[4];
    float* G = (float*)d_out;

    char* ws = (char*)d_ws;
    if (ws_size < (size_t)14753792) return;   // ~14.1 MiB
    short* qh  = (short*)(ws);                        // 4 MiB
    short* ql  = (short*)(ws + 4194304);              // 4 MiB
    short* qth = (short*)(ws + 8388608);              // 4 MiB
    float* sq   = (float*)(ws + 12582912);            // 32 KiB
    float* q2cp = (float*)(ws + 12615680);            // 2 MiB
    float* zup  = (float*)(ws + 14712832);            // 4 KiB
    float* zap  = (float*)(ws + 14716928);            // 4 KiB
    float* q2cv = (float*)(ws + 14721024);            // 32 KiB

    k0_split<<<dim3(4, 32), dim3(256), 0, stream>>>(q, W, qh, ql, qth, sq);
    k1<<<dim3(32, 32), dim3(512), 0, stream>>>(ctx, qmask, cmask, qh, ql, qth,
                                               sq, W, G, q2cp, zup, zap);
    k2c<<<dim3(32), dim3(256), 0, stream>>>(q2cp, zup, zap, q2cv);
    k3<<<dim3(128, 32), dim3(256), 0, stream>>>(ctx, q2cv, G);
}

// Round 5
// 172.758 us; speedup vs baseline: 1.6429x; 1.2093x over previous
//
#include <hip/hip_runtime.h>

// BiAttention (BiDAF) fused kernels for MI355X / gfx950.
// B=32, C_L=2048, Q_L=256, D=256. Output G = [B][C_L][4*D] fp32.
//
// Round 5:
// - Counted-vmcnt pipeline (T3+T4): raw s_barrier + explicit
//   s_waitcnt vmcnt(2)/lgkmcnt(0); staged loads stay 2 chunks in flight,
//   never drained inside the loop. __syncthreads only at phase boundaries.
// - LDS 50.7 KB -> 3 blocks/CU (launch_bounds(512,6) caps VGPR at 85).
// - S-GEMM drops the q-lo term (error ~1e-3); P stored bf16-hi in K-halves.
// - G0 + ctx pass folded into epilogue; setprio(1) around MFMA clusters.

#define CL 2048
#define QL 256
#define DD 256
#define TM 64
#define NEGV -1.0e7f

typedef short bs8 __attribute__((ext_vector_type(8)));
typedef float fx4 __attribute__((ext_vector_type(4)));

__device__ __forceinline__ short f2bf(float x) {
    unsigned u = __float_as_uint(x);
    unsigned r = (u + 0x7fffu + ((u >> 16) & 1u)) >> 16;   // RNE
    return (short)r;
}
__device__ __forceinline__ float bf2f(short h) {
    return __uint_as_float(((unsigned)(unsigned short)h) << 16);
}
__device__ __forceinline__ void gl16(const short* g, short* l) {
    __builtin_amdgcn_global_load_lds(
        (const __attribute__((address_space(1))) void*)g,
        (__attribute__((address_space(3))) void*)l, 16, 0, 0);
}
#define LGKM0() asm volatile("s_waitcnt lgkmcnt(0)" ::: "memory")
#define VMC2()  asm volatile("s_waitcnt vmcnt(2)" ::: "memory")
#define VMC0()  asm volatile("s_waitcnt vmcnt(0)" ::: "memory")

// ------------------------------------------- K0: split q (+ transposed) + s_q
__global__ void k0_split(const float* __restrict__ q, const float* __restrict__ W,
                         short* __restrict__ qh, short* __restrict__ qth,
                         float* __restrict__ sq) {
    __shared__ float lds[64][259];
    __shared__ float wq_l[256];
    int t = threadIdx.x, lane = t & 63, w = t >> 6;
    int b = blockIdx.y, cn = blockIdx.x;
    if (t < 64) *(fx4*)&wq_l[t * 4] = *(const fx4*)(W + 256 + t * 4);
    for (int r = 0; r < 64; ++r)
        lds[r][t] = q[((size_t)b * QL + cn * 64 + r) * DD + t];
    __syncthreads();
    for (int r = 0; r < 64; ++r) {
        size_t o = ((size_t)b * QL + cn * 64 + r) * DD + t;
        qh[o] = f2bf(lds[r][t]);
    }
    for (int dd = 0; dd < 64; ++dd) {
        int d = w * 64 + dd;
        size_t o = ((size_t)b * DD + d) * QL + cn * 64 + lane;
        qth[o] = f2bf(lds[lane][d]);
    }
    int r = t >> 2, qt = t & 3;
    float s = 0.0f;
    for (int i = 0; i < 64; ++i) {
        int colr = qt * 64 + ((i + r) & 63);
        s = fmaf(lds[r][colr], wq_l[colr], s);
    }
    s += __shfl_xor(s, 1, 64);
    s += __shfl_xor(s, 2, 64);
    if (qt == 0) sq[b * QL + cn * 64 + r] = s;
}

// ------------------------------------------------------------------- K1: main
// grid (32, 32): blockIdx.x = c-tile (64 rows), blockIdx.y = batch. 512 thr.
__global__ __launch_bounds__(512, 6) void k1(
        const float* __restrict__ ctx, const float* __restrict__ qmask,
        const float* __restrict__ cmask,
        const short* __restrict__ qh, const short* __restrict__ qth,
        const float* __restrict__ sq, const float* __restrict__ W,
        float* __restrict__ G, float* __restrict__ q2cp,
        float* __restrict__ zup, float* __restrict__ zap) {
    __shared__ __align__(16) char SMEM[50688];
    short* Bc   = (short*)SMEM;                 // [2][256][32] phase B
    short* Qt   = (short*)SMEM;                 // [2][256][32] phase C
    float* pout = (float*)SMEM;                 // [64][128]    epilogue
    float* sq_l  = (float*)(SMEM + 32768);      // 256
    float* qm_l  = sq_l + 256;                  // 256
    float* wcq_l = qm_l + 256;                  // 256
    float* wc_l  = wcq_l + 256;                 // 256
    float* sc_l  = wc_l + 256;                  // 64
    float* redA  = sc_l + 64;                   // [2][2][64]
    float* redB  = redA + 256;                  // [2][2][64]
    short* Pb    = (short*)(SMEM + 32768);      // [64][136] (overlays after sm)
    float* er_l  = (float*)(SMEM + 50176);      // 64
    float* zar_l = er_l + 64;                   // 64

    int t = threadIdx.x, lane = t & 63, wid = t >> 6;
    int wm = wid >> 1, wn = wid & 1;
    int l15 = lane & 15, lk = lane >> 4;
    int b = blockIdx.y, bx = blockIdx.x, c0 = bx * TM;

    if (t < 256) sq_l[t] = sq[b * QL + t];
    else qm_l[t - 256] = qmask[b * QL + (t - 256)];
    if (t < 64) *(fx4*)&wcq_l[t * 4] = *(const fx4*)(W + 512 + t * 4);
    else if (t < 128) *(fx4*)&wc_l[(t - 64) * 4] = *(const fx4*)(W + (t - 64) * 4);

    const short* qhb = qh + (size_t)b * QL * DD;
    const short* qtb = qth + (size_t)b * DD * QL;
    const float* ctxb = ctx + ((size_t)b * CL + c0) * DD;

    int srow = 32 * wid + (lane >> 2);
    int ssub = ((lane & 3) ^ ((srow >> 1) & 3)) << 3;   // source pre-swizzle

    auto stageB = [&](int p, int kk) {
        int co = kk * 32 + ssub;
        gl16(qhb + (size_t)srow * DD + co,        Bc + (p * 256 + 32 * wid) * 32);
        gl16(qhb + (size_t)(srow + 16) * DD + co, Bc + (p * 256 + 32 * wid + 16) * 32);
    };
    auto stageQ = [&](int p, int s) {
        int co = s * 32 + ssub;
        gl16(qtb + (size_t)srow * QL + co,        Qt + (p * 256 + 32 * wid) * 32);
        gl16(qtb + (size_t)(srow + 16) * QL + co, Qt + (p * 256 + 32 * wid + 16) * 32);
    };

    // ---------------- Phase B: S-GEMM, 8 chunks K=32, counted-vmcnt pipeline -
    fx4 acc[8];
#pragma unroll
    for (int i = 0; i < 8; ++i) acc[i] = (fx4)0.0f;
    float scp = 0.0f;
    int arow = 16 * wm + l15;
    const float* aptr = ctxb + (size_t)arow * DD + lk * 8;

    stageB(0, 0); stageB(1, 1);
    fx4 a0 = *(const fx4*)(aptr);
    fx4 a1 = *(const fx4*)(aptr + 4);
    __syncthreads();                    // full drain once (params + stage 0/1)

#pragma unroll
    for (int kk = 0; kk < 8; ++kk) {
        int cur = kk & 1;
        fx4 n0 = a0, n1 = a1;
        if (kk < 7) {
            n0 = *(const fx4*)(aptr + (kk + 1) * 32);
            n1 = *(const fx4*)(aptr + (kk + 1) * 32 + 4);
        }
        fx4 w0 = *(const fx4*)&wcq_l[kk * 32 + lk * 8];
        fx4 w1 = *(const fx4*)&wcq_l[kk * 32 + lk * 8 + 4];
        fx4 v0 = *(const fx4*)&wc_l[kk * 32 + lk * 8];
        fx4 v1 = *(const fx4*)&wc_l[kk * 32 + lk * 8 + 4];
        scp += a0[0] * v0[0] + a0[1] * v0[1] + a0[2] * v0[2] + a0[3] * v0[3]
             + a1[0] * v1[0] + a1[1] * v1[1] + a1[2] * v1[2] + a1[3] * v1[3];
        bs8 Ah, Al;
#pragma unroll
        for (int i = 0; i < 4; ++i) {
            float a = a0[i] * w0[i];
            short h = f2bf(a); Ah[i] = h; Al[i] = f2bf(a - bf2f(h));
            float c = a1[i] * w1[i];
            short h2 = f2bf(c); Ah[4 + i] = h2; Al[4 + i] = f2bf(c - bf2f(h2));
        }
        __builtin_amdgcn_s_setprio(1);
#pragma unroll
        for (int nt = 0; nt < 8; ++nt) {
            int col = 128 * wn + 16 * nt + l15;
            int ko = ((lk ^ ((col >> 1) & 3)) << 3);
            bs8 Bh = *(const bs8*)&Bc[(cur * 256 + col) * 32 + ko];
            acc[nt] = __builtin_amdgcn_mfma_f32_16x16x32_bf16(Ah, Bh, acc[nt], 0, 0, 0);
            acc[nt] = __builtin_amdgcn_mfma_f32_16x16x32_bf16(Al, Bh, acc[nt], 0, 0, 0);
        }
        __builtin_amdgcn_s_setprio(0);
        if (kk == 7) break;
        LGKM0();                              // my Bc reads landed
        __builtin_amdgcn_s_barrier();         // all readers done with buf[cur]
        if (kk < 6) { stageB(cur, kk + 2); VMC2(); }   // stage(kk+1) complete
        else        { VMC0(); }                         // tail: stage(7) done
        __builtin_amdgcn_s_barrier();         // stage(kk+1) visible to all
        a0 = n0; a1 = n1;
    }
    scp += __shfl_xor(scp, 16, 64);
    scp += __shfl_xor(scp, 32, 64);
    if (lk == 0 && wn == 0) sc_l[arow] = scp;
    __syncthreads();

    // ---------------- Softmax over q (qm folded into acc) -------------------
    float mall[4], mu[4], scv[4];
#pragma unroll
    for (int j = 0; j < 4; ++j) {
        mall[j] = -3.0e38f; mu[j] = -3.0e38f;
        scv[j] = sc_l[16 * wm + 4 * lk + j];
    }
#pragma unroll
    for (int nt = 0; nt < 8; ++nt) {
        int col = 128 * wn + 16 * nt + l15;
        float sqv = sq_l[col], qmv = qm_l[col];
#pragma unroll
        for (int j = 0; j < 4; ++j) {
            float S = acc[nt][j] + scv[j] + sqv;
            float xm = S * qmv;
            float ms = (qmv != 0.0f) ? S : NEGV;
            acc[nt][j] = xm;
            mall[j] = fmaxf(mall[j], xm);
            mu[j]   = fmaxf(mu[j], ms);
        }
    }
#pragma unroll
    for (int s = 1; s <= 8; s <<= 1)
#pragma unroll
        for (int j = 0; j < 4; ++j) {
            mall[j] = fmaxf(mall[j], __shfl_xor(mall[j], s, 64));
            mu[j]   = fmaxf(mu[j],   __shfl_xor(mu[j], s, 64));
        }
    if (l15 == 0)
#pragma unroll
        for (int j = 0; j < 4; ++j) {
            redA[wn * 128 + 0 * 64 + 16 * wm + 4 * lk + j] = mall[j];
            redA[wn * 128 + 1 * 64 + 16 * wm + 4 * lk + j] = mu[j];
        }
    __syncthreads();
#pragma unroll
    for (int j = 0; j < 4; ++j) {
        int row = 16 * wm + 4 * lk + j;
        mall[j] = fmaxf(redA[row], redA[128 + row]);
        mu[j]   = fmaxf(redA[64 + row], redA[192 + row]);
    }
    if (wn == 0 && l15 == 0)
#pragma unroll
        for (int j = 0; j < 4; ++j) {
            int row = 16 * wm + 4 * lk + j;
            smaxw: ;
            float cm = cmask[(size_t)b * CL + c0 + row];
            float e  = (cm != 0.0f) ? __expf(mu[j] - 32.0f) : 0.0f;
            er_l[row]  = e;
            zar_l[row] = (cm != 0.0f) ? e : 1.2664166e-14f;   // exp(-32)
        }

    float zal[4] = {0, 0, 0, 0}, zum[4] = {0, 0, 0, 0};
#pragma unroll
    for (int nt = 0; nt < 8; ++nt) {
        int col = 128 * wn + 16 * nt + l15;
        float qmv = qm_l[col];
#pragma unroll
        for (int j = 0; j < 4; ++j) {
            float e = __expf(acc[nt][j] - mall[j]);
            acc[nt][j] = e * qmv;                 // qm folded for P and zum
            zal[j] += e;
            zum[j] += acc[nt][j];
        }
    }
#pragma unroll
    for (int s = 1; s <= 8; s <<= 1)
#pragma unroll
        for (int j = 0; j < 4; ++j) {
            zal[j] += __shfl_xor(zal[j], s, 64);
            zum[j] += __shfl_xor(zum[j], s, 64);
        }
    if (l15 == 0)
#pragma unroll
        for (int j = 0; j < 4; ++j) {
            redB[wn * 128 + 0 * 64 + 16 * wm + 4 * lk + j] = zal[j];
            redB[wn * 128 + 1 * 64 + 16 * wm + 4 * lk + j] = zum[j];
        }
    __syncthreads();
    float inv[4];
#pragma unroll
    for (int j = 0; j < 4; ++j) {
        int row = 16 * wm + 4 * lk + j;
        float Za = redB[row] + redB[128 + row];
        float Zu = redB[64 + row] + redB[192 + row];
        inv[j] = 1.0f / (Zu + 1e-13f * Za);
    }
    __syncthreads();                 // protect R1 overlay (Pb clobbers redB..)

    // ---------------- Phase C: c2q, K-halves, counted-vmcnt pipeline --------
    int prow = 16 * wm + l15;
    if (wn == 0) {                                   // P half 0 (k-cols 0..127)
#pragma unroll
        for (int nt = 0; nt < 8; ++nt)
#pragma unroll
            for (int j = 0; j < 4; ++j)
                Pb[(16 * wm + 4 * lk + j) * 136 + 16 * nt + l15] =
                    f2bf(acc[nt][j] * inv[j]);
    }
    stageQ(0, 0); stageQ(1, 1);
    __syncthreads();                  // full drain: P visible + Qt(0,1) done

    fx4 acc2[8];
#pragma unroll
    for (int i = 0; i < 8; ++i) acc2[i] = (fx4)0.0f;
#pragma unroll
    for (int s = 0; s < 8; ++s) {
        int cur = s & 1, k2 = s & 3;
        bs8 Ph = *(const bs8*)&Pb[prow * 136 + k2 * 32 + lk * 8];
        __builtin_amdgcn_s_setprio(1);
#pragma unroll
        for (int nt = 0; nt < 8; ++nt) {
            int d = 128 * wn + 16 * nt + l15;
            int ko = ((lk ^ ((d >> 1) & 3)) << 3);
            bs8 Bh = *(const bs8*)&Qt[(cur * 256 + d) * 32 + ko];
            acc2[nt] = __builtin_amdgcn_mfma_f32_16x16x32_bf16(Ph, Bh, acc2[nt], 0, 0, 0);
        }
        __builtin_amdgcn_s_setprio(0);
        if (s == 7) break;
        LGKM0();
        __builtin_amdgcn_s_barrier();          // readers done with Qt[cur]/Pb
        if (s < 6) stageQ(cur, s + 2);
        if (s == 3) {                          // swap P to half 1 (k 128..255)
            if (wn == 1) {
#pragma unroll
                for (int nt = 0; nt < 8; ++nt)
#pragma unroll
                    for (int j = 0; j < 4; ++j)
                        Pb[(16 * wm + 4 * lk + j) * 136 + 16 * nt + l15] =
                            f2bf(acc[nt][j] * inv[j]);
            }
            LGKM0();                           // P writes landed
        }
        if (s < 6) { VMC2(); } else { VMC0(); }
        __builtin_amdgcn_s_barrier();          // stage(s+1) + P visible
    }
    __syncthreads();                           // Qt dead; pout may overwrite R0

    // ---------------- Epilogue: G0/G1/G2 in d-halves ------------------------
    int erow = t >> 3, eu = t & 7;
    for (int h = 0; h < 2; ++h) {
        if (h) __syncthreads();
        if (wn == h) {
#pragma unroll
            for (int nt = 0; nt < 8; ++nt)
#pragma unroll
                for (int j = 0; j < 4; ++j) {
                    int row = 16 * wm + 4 * lk + j;
                    int col = 16 * nt + l15;
                    pout[row * 128 + (col ^ ((row & 7) << 2))] = acc2[nt][j];
                }
        }
        __syncthreads();
        size_t grow = (size_t)b * CL + c0 + erow;
#pragma unroll
        for (int kkl = 0; kkl < 4; ++kkl) {
            int colL = kkl * 32 + eu * 4;
            fx4 cv = *(const fx4*)&ctxb[(size_t)erow * DD + 128 * h + colL];
            fx4 pv = *(const fx4*)&pout[erow * 128 + kkl * 32 + (eu ^ (erow & 7)) * 4];
            float* gb = G + grow * 1024;
            *(fx4*)&gb[      128 * h + colL] = cv;
            *(fx4*)&gb[256 + 128 * h + colL] = pv;
            fx4 p2; p2[0] = cv[0] * pv[0]; p2[1] = cv[1] * pv[1];
            p2[2] = cv[2] * pv[2]; p2[3] = cv[3] * pv[3];
            *(fx4*)&gb[512 + 128 * h + colL] = p2;
        }
    }

    // ---------------- q2c partials: Sum_r e_r * c[r][col], Zu/Za ------------
    int colq = t & 255, rh = t >> 8;
    float accq = 0.0f;
#pragma unroll 8
    for (int r = rh * 32; r < rh * 32 + 32; ++r)
        accq = fmaf(er_l[r], ctxb[(size_t)r * DD + colq], accq);
    q2cp[(((size_t)b * 32 + bx) * 2 + rh) * 256 + colq] = accq;
    if (t < 64) {
        float e = er_l[t], za = zar_l[t];
#pragma unroll
        for (int sft = 32; sft >= 1; sft >>= 1) {
            e  += __shfl_xor(e, sft, 64);
            za += __shfl_xor(za, sft, 64);
        }
        if (t == 0) { zup[b * 32 + bx] = e; zap[b * 32 + bx] = za; }
    }
}

// ------------------------------------------------- K2c: finalize q2c (determ.)
__global__ void k2c(const float* __restrict__ q2cp, const float* __restrict__ zup,
                    const float* __restrict__ zap, float* __restrict__ q2c) {
    int t = threadIdx.x, b = blockIdx.x;
    float zu = 0.0f, za = 0.0f;
    for (int i = 0; i < 32; ++i) { zu += zup[b * 32 + i]; za += zap[b * 32 + i]; }
    float inv = 1.0f / (zu + 1e-13f * za);
    float s = 0.0f;
    for (int p = 0; p < 64; ++p) s += q2cp[((size_t)b * 64 + p) * 256 + t];
    q2c[b * DD + t] = s * inv;
}

// ------------------------------------------------- K3: G part 3 = c * q2c
__global__ void k3(const float* __restrict__ ctx, const float* __restrict__ q2c,
                   float* __restrict__ G) {
    __shared__ float4 qv[64];
    int t = threadIdx.x, lane = t & 63, w = t >> 6;
    int b = blockIdx.y;
    if (t < 64) qv[t] = ((const float4*)q2c)[b * 64 + t];
    __syncthreads();
    int c0 = blockIdx.x * 16;
    float4 q4 = qv[lane];
    for (int r = w; r < 16; r += 4) {
        size_t grow = (size_t)b * CL + c0 + r;
        float4 cv = ((const float4*)ctx)[grow * 64 + lane];
        float4 o;
        o.x = cv.x * q4.x; o.y = cv.y * q4.y;
        o.z = cv.z * q4.z; o.w = cv.w * q4.w;
        ((float4*)G)[grow * 256 + 192 + lane] = o;
    }
}

extern "C" void kernel_launch(void* const* d_in, const int* in_sizes, int n_in,
                              void* d_out, int out_size, void* d_ws, size_t ws_size,
                              hipStream_t stream) {
    const float* ctx   = (const float*)d_in[0];
    const float* cmask = (const float*)d_in[1];
    const float* q     = (const float*)d_in[2];
    const float* qmask = (const float*)d_in[3];
    const float* W     = (const float*)d_in[4];
    float* G = (float*)d_out;

    char* ws = (char*)d_ws;
    if (ws_size < (size_t)10559488) return;   // ~10.1 MiB
    short* qh  = (short*)(ws);                        // 4 MiB
    short* qth = (short*)(ws + 4194304);              // 4 MiB
    float* sq   = (float*)(ws + 8388608);             // 32 KiB
    float* q2cp = (float*)(ws + 8421376);             // 2 MiB
    float* zup  = (float*)(ws + 10518528);            // 4 KiB
    float* zap  = (float*)(ws + 10522624);            // 4 KiB
    float* q2cv = (float*)(ws + 10526720);            // 32 KiB

    k0_split<<<dim3(4, 32), dim3(256), 0, stream>>>(q, W, qh, qth, sq);
    k1<<<dim3(32, 32), dim3(512), 0, stream>>>(ctx, qmask, cmask, qh, qth,
                                               sq, W, G, q2cp, zup, zap);
    k2c<<<dim3(32), dim3(256), 0, stream>>>(q2cp, zup, zap, q2cv);
    k3<<<dim3(128, 32), dim3(256), 0, stream>>>(ctx, q2cv, G);
}

// Round 6
// 157.399 us; speedup vs baseline: 1.8032x; 1.0976x over previous
//
#include <hip/hip_runtime.h>

// BiAttention (BiDAF) fused kernels for MI355X / gfx950.
// B=32, C_L=2048, Q_L=256, D=256. Output G = [B][C_L][4*D] fp32.
//
// Round 6:
// - XCD-aware swizzle in k1: HW ids with residue r (mod 8) -> XCD r handle
//   batches 4r..4r+3 only => each batch's qh/qth stream is fetched by ONE
//   XCD and stays L2-resident (kills the ~100 MB q re-fetch).
// - Nontemporal stores for all G writes (k1 epilogue, k3) and q2cp; G is
//   write-once => stop evicting ctx/q from the 4 MiB per-XCD L2.
// - Counted-vmcnt pipeline (T3+T4), setprio, swizzled LDS as round 5.

#define CL 2048
#define QL 256
#define DD 256
#define TM 64
#define NEGV -1.0e7f

typedef short bs8 __attribute__((ext_vector_type(8)));
typedef float fx4 __attribute__((ext_vector_type(4)));

__device__ __forceinline__ short f2bf(float x) {
    unsigned u = __float_as_uint(x);
    unsigned r = (u + 0x7fffu + ((u >> 16) & 1u)) >> 16;   // RNE
    return (short)r;
}
__device__ __forceinline__ float bf2f(short h) {
    return __uint_as_float(((unsigned)(unsigned short)h) << 16);
}
__device__ __forceinline__ void gl16(const short* g, short* l) {
    __builtin_amdgcn_global_load_lds(
        (const __attribute__((address_space(1))) void*)g,
        (__attribute__((address_space(3))) void*)l, 16, 0, 0);
}
#define LGKM0() asm volatile("s_waitcnt lgkmcnt(0)" ::: "memory")
#define VMC2()  asm volatile("s_waitcnt vmcnt(2)" ::: "memory")
#define VMC0()  asm volatile("s_waitcnt vmcnt(0)" ::: "memory")

// ------------------------------------------- K0: split q (+ transposed) + s_q
__global__ void k0_split(const float* __restrict__ q, const float* __restrict__ W,
                         short* __restrict__ qh, short* __restrict__ qth,
                         float* __restrict__ sq) {
    __shared__ float lds[64][259];
    __shared__ float wq_l[256];
    int t = threadIdx.x, lane = t & 63, w = t >> 6;
    int b = blockIdx.y, cn = blockIdx.x;
    if (t < 64) *(fx4*)&wq_l[t * 4] = *(const fx4*)(W + 256 + t * 4);
    for (int r = 0; r < 64; ++r)
        lds[r][t] = q[((size_t)b * QL + cn * 64 + r) * DD + t];
    __syncthreads();
    for (int r = 0; r < 64; ++r) {
        size_t o = ((size_t)b * QL + cn * 64 + r) * DD + t;
        qh[o] = f2bf(lds[r][t]);
    }
    for (int dd = 0; dd < 64; ++dd) {
        int d = w * 64 + dd;
        size_t o = ((size_t)b * DD + d) * QL + cn * 64 + lane;
        qth[o] = f2bf(lds[lane][d]);
    }
    int r = t >> 2, qt = t & 3;
    float s = 0.0f;
    for (int i = 0; i < 64; ++i) {
        int colr = qt * 64 + ((i + r) & 63);
        s = fmaf(lds[r][colr], wq_l[colr], s);
    }
    s += __shfl_xor(s, 1, 64);
    s += __shfl_xor(s, 2, 64);
    if (qt == 0) sq[b * QL + cn * 64 + r] = s;
}

// ------------------------------------------------------------------- K1: main
// grid (1024): XCD-aware remap -> (batch, tile). 512 thr.
__global__ __launch_bounds__(512, 6) void k1(
        const float* __restrict__ ctx, const float* __restrict__ qmask,
        const float* __restrict__ cmask,
        const short* __restrict__ qh, const short* __restrict__ qth,
        const float* __restrict__ sq, const float* __restrict__ W,
        float* __restrict__ G, float* __restrict__ q2cp,
        float* __restrict__ zup, float* __restrict__ zap) {
    __shared__ __align__(16) char SMEM[50688];
    short* Bc   = (short*)SMEM;                 // [2][256][32] phase B
    short* Qt   = (short*)SMEM;                 // [2][256][32] phase C
    float* pout = (float*)SMEM;                 // [64][128]    epilogue
    float* sq_l  = (float*)(SMEM + 32768);      // 256
    float* qm_l  = sq_l + 256;                  // 256
    float* wcq_l = qm_l + 256;                  // 256
    float* wc_l  = wcq_l + 256;                 // 256
    float* sc_l  = wc_l + 256;                  // 64
    float* redA  = sc_l + 64;                   // [2][2][64]
    float* redB  = redA + 256;                  // [2][2][64]
    short* Pb    = (short*)(SMEM + 32768);      // [64][136] (overlays after sm)
    float* er_l  = (float*)(SMEM + 50176);      // 64
    float* zar_l = er_l + 64;                   // 64

    int t = threadIdx.x, lane = t & 63, wid = t >> 6;
    int wm = wid >> 1, wn = wid & 1;
    int l15 = lane & 15, lk = lane >> 4;
    // XCD-aware remap: HW id residue r (mod 8) -> batches 4r..4r+3.
    int id = blockIdx.x;
    int xcd = id & 7, j = id >> 3;
    int b = xcd * 4 + (j >> 5);
    int bx = j & 31;
    int c0 = bx * TM;

    if (t < 256) sq_l[t] = sq[b * QL + t];
    else qm_l[t - 256] = qmask[b * QL + (t - 256)];
    if (t < 64) *(fx4*)&wcq_l[t * 4] = *(const fx4*)(W + 512 + t * 4);
    else if (t < 128) *(fx4*)&wc_l[(t - 64) * 4] = *(const fx4*)(W + (t - 64) * 4);

    const short* qhb = qh + (size_t)b * QL * DD;
    const short* qtb = qth + (size_t)b * DD * QL;
    const float* ctxb = ctx + ((size_t)b * CL + c0) * DD;

    int srow = 32 * wid + (lane >> 2);
    int ssub = ((lane & 3) ^ ((srow >> 1) & 3)) << 3;   // source pre-swizzle

    auto stageB = [&](int p, int kk) {
        int co = kk * 32 + ssub;
        gl16(qhb + (size_t)srow * DD + co,        Bc + (p * 256 + 32 * wid) * 32);
        gl16(qhb + (size_t)(srow + 16) * DD + co, Bc + (p * 256 + 32 * wid + 16) * 32);
    };
    auto stageQ = [&](int p, int s) {
        int co = s * 32 + ssub;
        gl16(qtb + (size_t)srow * QL + co,        Qt + (p * 256 + 32 * wid) * 32);
        gl16(qtb + (size_t)(srow + 16) * QL + co, Qt + (p * 256 + 32 * wid + 16) * 32);
    };

    // ---------------- Phase B: S-GEMM, 8 chunks K=32, counted-vmcnt pipeline -
    fx4 acc[8];
#pragma unroll
    for (int i = 0; i < 8; ++i) acc[i] = (fx4)0.0f;
    float scp = 0.0f;
    int arow = 16 * wm + l15;
    const float* aptr = ctxb + (size_t)arow * DD + lk * 8;

    stageB(0, 0); stageB(1, 1);
    fx4 a0 = *(const fx4*)(aptr);
    fx4 a1 = *(const fx4*)(aptr + 4);
    __syncthreads();                    // full drain once (params + stage 0/1)

#pragma unroll
    for (int kk = 0; kk < 8; ++kk) {
        int cur = kk & 1;
        fx4 n0 = a0, n1 = a1;
        if (kk < 7) {
            n0 = *(const fx4*)(aptr + (kk + 1) * 32);
            n1 = *(const fx4*)(aptr + (kk + 1) * 32 + 4);
        }
        fx4 w0 = *(const fx4*)&wcq_l[kk * 32 + lk * 8];
        fx4 w1 = *(const fx4*)&wcq_l[kk * 32 + lk * 8 + 4];
        fx4 v0 = *(const fx4*)&wc_l[kk * 32 + lk * 8];
        fx4 v1 = *(const fx4*)&wc_l[kk * 32 + lk * 8 + 4];
        scp += a0[0] * v0[0] + a0[1] * v0[1] + a0[2] * v0[2] + a0[3] * v0[3]
             + a1[0] * v1[0] + a1[1] * v1[1] + a1[2] * v1[2] + a1[3] * v1[3];
        bs8 Ah, Al;
#pragma unroll
        for (int i = 0; i < 4; ++i) {
            float a = a0[i] * w0[i];
            short h = f2bf(a); Ah[i] = h; Al[i] = f2bf(a - bf2f(h));
            float c = a1[i] * w1[i];
            short h2 = f2bf(c); Ah[4 + i] = h2; Al[4 + i] = f2bf(c - bf2f(h2));
        }
        __builtin_amdgcn_s_setprio(1);
#pragma unroll
        for (int nt = 0; nt < 8; ++nt) {
            int col = 128 * wn + 16 * nt + l15;
            int ko = ((lk ^ ((col >> 1) & 3)) << 3);
            bs8 Bh = *(const bs8*)&Bc[(cur * 256 + col) * 32 + ko];
            acc[nt] = __builtin_amdgcn_mfma_f32_16x16x32_bf16(Ah, Bh, acc[nt], 0, 0, 0);
            acc[nt] = __builtin_amdgcn_mfma_f32_16x16x32_bf16(Al, Bh, acc[nt], 0, 0, 0);
        }
        __builtin_amdgcn_s_setprio(0);
        if (kk == 7) break;
        LGKM0();                              // my Bc reads landed
        __builtin_amdgcn_s_barrier();         // all readers done with buf[cur]
        if (kk < 6) { stageB(cur, kk + 2); VMC2(); }   // stage(kk+1) complete
        else        { VMC0(); }                         // tail: stage(7) done
        __builtin_amdgcn_s_barrier();         // stage(kk+1) visible to all
        a0 = n0; a1 = n1;
    }
    scp += __shfl_xor(scp, 16, 64);
    scp += __shfl_xor(scp, 32, 64);
    if (lk == 0 && wn == 0) sc_l[arow] = scp;
    __syncthreads();

    // ---------------- Softmax over q (qm folded into acc) -------------------
    float mall[4], mu[4], scv[4];
#pragma unroll
    for (int j2 = 0; j2 < 4; ++j2) {
        mall[j2] = -3.0e38f; mu[j2] = -3.0e38f;
        scv[j2] = sc_l[16 * wm + 4 * lk + j2];
    }
#pragma unroll
    for (int nt = 0; nt < 8; ++nt) {
        int col = 128 * wn + 16 * nt + l15;
        float sqv = sq_l[col], qmv = qm_l[col];
#pragma unroll
        for (int j2 = 0; j2 < 4; ++j2) {
            float S = acc[nt][j2] + scv[j2] + sqv;
            float xm = S * qmv;
            float ms = (qmv != 0.0f) ? S : NEGV;
            acc[nt][j2] = xm;
            mall[j2] = fmaxf(mall[j2], xm);
            mu[j2]   = fmaxf(mu[j2], ms);
        }
    }
#pragma unroll
    for (int s = 1; s <= 8; s <<= 1)
#pragma unroll
        for (int j2 = 0; j2 < 4; ++j2) {
            mall[j2] = fmaxf(mall[j2], __shfl_xor(mall[j2], s, 64));
            mu[j2]   = fmaxf(mu[j2],   __shfl_xor(mu[j2], s, 64));
        }
    if (l15 == 0)
#pragma unroll
        for (int j2 = 0; j2 < 4; ++j2) {
            redA[wn * 128 + 0 * 64 + 16 * wm + 4 * lk + j2] = mall[j2];
            redA[wn * 128 + 1 * 64 + 16 * wm + 4 * lk + j2] = mu[j2];
        }
    __syncthreads();
#pragma unroll
    for (int j2 = 0; j2 < 4; ++j2) {
        int row = 16 * wm + 4 * lk + j2;
        mall[j2] = fmaxf(redA[row], redA[128 + row]);
        mu[j2]   = fmaxf(redA[64 + row], redA[192 + row]);
    }
    if (wn == 0 && l15 == 0)
#pragma unroll
        for (int j2 = 0; j2 < 4; ++j2) {
            int row = 16 * wm + 4 * lk + j2;
            float cm = cmask[(size_t)b * CL + c0 + row];
            float e  = (cm != 0.0f) ? __expf(mu[j2] - 32.0f) : 0.0f;
            er_l[row]  = e;
            zar_l[row] = (cm != 0.0f) ? e : 1.2664166e-14f;   // exp(-32)
        }

    float zal[4] = {0, 0, 0, 0}, zum[4] = {0, 0, 0, 0};
#pragma unroll
    for (int nt = 0; nt < 8; ++nt) {
        int col = 128 * wn + 16 * nt + l15;
        float qmv = qm_l[col];
#pragma unroll
        for (int j2 = 0; j2 < 4; ++j2) {
            float e = __expf(acc[nt][j2] - mall[j2]);
            acc[nt][j2] = e * qmv;                 // qm folded for P and zum
            zal[j2] += e;
            zum[j2] += acc[nt][j2];
        }
    }
#pragma unroll
    for (int s = 1; s <= 8; s <<= 1)
#pragma unroll
        for (int j2 = 0; j2 < 4; ++j2) {
            zal[j2] += __shfl_xor(zal[j2], s, 64);
            zum[j2] += __shfl_xor(zum[j2], s, 64);
        }
    if (l15 == 0)
#pragma unroll
        for (int j2 = 0; j2 < 4; ++j2) {
            redB[wn * 128 + 0 * 64 + 16 * wm + 4 * lk + j2] = zal[j2];
            redB[wn * 128 + 1 * 64 + 16 * wm + 4 * lk + j2] = zum[j2];
        }
    __syncthreads();
    float inv[4];
#pragma unroll
    for (int j2 = 0; j2 < 4; ++j2) {
        int row = 16 * wm + 4 * lk + j2;
        float Za = redB[row] + redB[128 + row];
        float Zu = redB[64 + row] + redB[192 + row];
        inv[j2] = 1.0f / (Zu + 1e-13f * Za);
    }
    __syncthreads();                 // protect R1 overlay (Pb clobbers redB..)

    // ---------------- Phase C: c2q, K-halves, counted-vmcnt pipeline --------
    int prow = 16 * wm + l15;
    if (wn == 0) {                                   // P half 0 (k-cols 0..127)
#pragma unroll
        for (int nt = 0; nt < 8; ++nt)
#pragma unroll
            for (int j2 = 0; j2 < 4; ++j2)
                Pb[(16 * wm + 4 * lk + j2) * 136 + 16 * nt + l15] =
                    f2bf(acc[nt][j2] * inv[j2]);
    }
    stageQ(0, 0); stageQ(1, 1);
    __syncthreads();                  // full drain: P visible + Qt(0,1) done

    fx4 acc2[8];
#pragma unroll
    for (int i = 0; i < 8; ++i) acc2[i] = (fx4)0.0f;
#pragma unroll
    for (int s = 0; s < 8; ++s) {
        int cur = s & 1, k2 = s & 3;
        bs8 Ph = *(const bs8*)&Pb[prow * 136 + k2 * 32 + lk * 8];
        __builtin_amdgcn_s_setprio(1);
#pragma unroll
        for (int nt = 0; nt < 8; ++nt) {
            int d = 128 * wn + 16 * nt + l15;
            int ko = ((lk ^ ((d >> 1) & 3)) << 3);
            bs8 Bh = *(const bs8*)&Qt[(cur * 256 + d) * 32 + ko];
            acc2[nt] = __builtin_amdgcn_mfma_f32_16x16x32_bf16(Ph, Bh, acc2[nt], 0, 0, 0);
        }
        __builtin_amdgcn_s_setprio(0);
        if (s == 7) break;
        LGKM0();
        __builtin_amdgcn_s_barrier();          // readers done with Qt[cur]/Pb
        if (s < 6) stageQ(cur, s + 2);
        if (s == 3) {                          // swap P to half 1 (k 128..255)
            if (wn == 1) {
#pragma unroll
                for (int nt = 0; nt < 8; ++nt)
#pragma unroll
                    for (int j2 = 0; j2 < 4; ++j2)
                        Pb[(16 * wm + 4 * lk + j2) * 136 + 16 * nt + l15] =
                            f2bf(acc[nt][j2] * inv[j2]);
            }
            LGKM0();                           // P writes landed
        }
        if (s < 6) { VMC2(); } else { VMC0(); }
        __builtin_amdgcn_s_barrier();          // stage(s+1) + P visible
    }
    __syncthreads();                           // Qt dead; pout may overwrite R0

    // ---------------- Epilogue: G0/G1/G2 in d-halves (nontemporal) ----------
    int erow = t >> 3, eu = t & 7;
    for (int h = 0; h < 2; ++h) {
        if (h) __syncthreads();
        if (wn == h) {
#pragma unroll
            for (int nt = 0; nt < 8; ++nt)
#pragma unroll
                for (int j2 = 0; j2 < 4; ++j2) {
                    int row = 16 * wm + 4 * lk + j2;
                    int col = 16 * nt + l15;
                    pout[row * 128 + (col ^ ((row & 7) << 2))] = acc2[nt][j2];
                }
        }
        __syncthreads();
        size_t grow = (size_t)b * CL + c0 + erow;
#pragma unroll
        for (int kkl = 0; kkl < 4; ++kkl) {
            int colL = kkl * 32 + eu * 4;
            fx4 cv = *(const fx4*)&ctxb[(size_t)erow * DD + 128 * h + colL];
            fx4 pv = *(const fx4*)&pout[erow * 128 + kkl * 32 + (eu ^ (erow & 7)) * 4];
            float* gb = G + grow * 1024;
            __builtin_nontemporal_store(cv, (fx4*)&gb[128 * h + colL]);
            __builtin_nontemporal_store(pv, (fx4*)&gb[256 + 128 * h + colL]);
            fx4 p2; p2[0] = cv[0] * pv[0]; p2[1] = cv[1] * pv[1];
            p2[2] = cv[2] * pv[2]; p2[3] = cv[3] * pv[3];
            __builtin_nontemporal_store(p2, (fx4*)&gb[512 + 128 * h + colL]);
        }
    }

    // ---------------- q2c partials: Sum_r e_r * c[r][col], Zu/Za ------------
    int colq = t & 255, rh = t >> 8;
    float accq = 0.0f;
#pragma unroll 8
    for (int r = rh * 32; r < rh * 32 + 32; ++r)
        accq = fmaf(er_l[r], ctxb[(size_t)r * DD + colq], accq);
    __builtin_nontemporal_store(
        accq, &q2cp[(((size_t)b * 32 + bx) * 2 + rh) * 256 + colq]);
    if (t < 64) {
        float e = er_l[t], za = zar_l[t];
#pragma unroll
        for (int sft = 32; sft >= 1; sft >>= 1) {
            e  += __shfl_xor(e, sft, 64);
            za += __shfl_xor(za, sft, 64);
        }
        if (t == 0) { zup[b * 32 + bx] = e; zap[b * 32 + bx] = za; }
    }
}

// ------------------------------------------------- K2c: finalize q2c (determ.)
__global__ void k2c(const float* __restrict__ q2cp, const float* __restrict__ zup,
                    const float* __restrict__ zap, float* __restrict__ q2c) {
    int t = threadIdx.x, b = blockIdx.x;
    float zu = 0.0f, za = 0.0f;
    for (int i = 0; i < 32; ++i) { zu += zup[b * 32 + i]; za += zap[b * 32 + i]; }
    float inv = 1.0f / (zu + 1e-13f * za);
    float s = 0.0f;
    for (int p = 0; p < 64; ++p) s += q2cp[((size_t)b * 64 + p) * 256 + t];
    q2c[b * DD + t] = s * inv;
}

// ------------------------------------------------- K3: G part 3 = c * q2c
__global__ void k3(const float* __restrict__ ctx, const float* __restrict__ q2c,
                   float* __restrict__ G) {
    __shared__ fx4 qv[64];
    int t = threadIdx.x, lane = t & 63, w = t >> 6;
    int b = blockIdx.y;
    if (t < 64) qv[t] = ((const fx4*)q2c)[b * 64 + t];
    __syncthreads();
    int c0 = blockIdx.x * 16;
    fx4 q4 = qv[lane];
    for (int r = w; r < 16; r += 4) {
        size_t grow = (size_t)b * CL + c0 + r;
        fx4 cv = __builtin_nontemporal_load(((const fx4*)ctx) + grow * 64 + lane);
        fx4 o;
        o[0] = cv[0] * q4[0]; o[1] = cv[1] * q4[1];
        o[2] = cv[2] * q4[2]; o[3] = cv[3] * q4[3];
        __builtin_nontemporal_store(o, ((fx4*)G) + grow * 256 + 192 + lane);
    }
}

extern "C" void kernel_launch(void* const* d_in, const int* in_sizes, int n_in,
                              void* d_out, int out_size, void* d_ws, size_t ws_size,
                              hipStream_t stream) {
    const float* ctx   = (const float*)d_in[0];
    const float* cmask = (const float*)d_in[1];
    const float* q     = (const float*)d_in[2];
    const float* qmask = (const float*)d_in[3];
    const float* W     = (const float*)d_in[4];
    float* G = (float*)d_out;

    char* ws = (char*)d_ws;
    if (ws_size < (size_t)10559488) return;   // ~10.1 MiB
    short* qh  = (short*)(ws);                        // 4 MiB
    short* qth = (short*)(ws + 4194304);              // 4 MiB
    float* sq   = (float*)(ws + 8388608);             // 32 KiB
    float* q2cp = (float*)(ws + 8421376);             // 2 MiB
    float* zup  = (float*)(ws + 10518528);            // 4 KiB
    float* zap  = (float*)(ws + 10522624);            // 4 KiB
    float* q2cv = (float*)(ws + 10526720);            // 32 KiB

    k0_split<<<dim3(4, 32), dim3(256), 0, stream>>>(q, W, qh, qth, sq);
    k1<<<dim3(1024), dim3(512), 0, stream>>>(ctx, qmask, cmask, qh, qth,
                                             sq, W, G, q2cp, zup, zap);
    k2c<<<dim3(32), dim3(256), 0, stream>>>(q2cp, zup, zap, q2cv);
    k3<<<dim3(128, 32), dim3(256), 0, stream>>>(ctx, q2cv, G);
}